// Round 2
// baseline (665.787 us; speedup 1.0000x reference)
//
#include <hip/hip_runtime.h>

// Problem constants (from reference setup_inputs)
#define SEQ 2048
#define BATCH 64
#define DIM 1024

#define SPW 16                   // s-rows per wave
#define WPB 4                    // waves per block (256 threads)
#define SPB (SPW * WPB)          // 64 s-rows per block
#define CHUNKS (SEQ / SPB)       // 32
#define ROW_F4 (BATCH * DIM / 4) // float4 stride between consecutive s rows

// clang ext-vector float4 (required by __builtin_nontemporal_load; the HIP
// float4 struct type is rejected by the builtin)
typedef float f4 __attribute__((ext_vector_type(4)));

// energies[b, s] = dot(hidden[b, :], enc[s, b, :])
// One block per (b, 64-row s-chunk). hidden[b] (1024 floats) is loaded ONCE
// into registers (16 floats/lane) and reused for all 64 rows. Each wave
// processes 16 rows, unrolled 4 at a time -> 16 independent float4 enc loads
// in flight per wave, and 4 independent shuffle-reduce chains that hide each
// other's latency. enc is a pure read-once stream -> nontemporal loads so
// it doesn't evict the L2-resident hidden.
__global__ __launch_bounds__(256) void energies_kernel(
    const float* __restrict__ hidden,   // [BATCH, DIM]
    const float* __restrict__ enc,      // [SEQ, BATCH, DIM]
    float* __restrict__ out)            // [BATCH, SEQ] energies (pre-softmax)
{
    const int wave = threadIdx.x >> 6;
    const int lane = threadIdx.x & 63;
    const int b     = blockIdx.x & (BATCH - 1);  // b fastest: concurrent
    const int chunk = blockIdx.x >> 6;           // blocks stream one s-slab
    const int s_base = chunk * SPB + wave * SPW;

    // hidden[b] resident in registers: lane holds floats {lane, 64+lane, ...}*4
    const f4* __restrict__ h4 = (const f4*)(hidden + (size_t)b * DIM);
    const f4 h0 = h4[lane];
    const f4 h1 = h4[64 + lane];
    const f4 h2 = h4[128 + lane];
    const f4 h3 = h4[192 + lane];

    const f4* __restrict__ e0 =
        (const f4*)(enc + ((size_t)s_base * BATCH + b) * DIM) + lane;

    for (int i = 0; i < SPW; i += 4) {
        float acc[4];
#pragma unroll
        for (int u = 0; u < 4; ++u) {
            const f4* __restrict__ e = e0 + (size_t)(i + u) * ROW_F4;
            f4 a = __builtin_nontemporal_load(e);
            f4 c = __builtin_nontemporal_load(e + 64);
            f4 d = __builtin_nontemporal_load(e + 128);
            f4 f = __builtin_nontemporal_load(e + 192);
            acc[u] = a.x * h0.x + a.y * h0.y + a.z * h0.z + a.w * h0.w
                   + c.x * h1.x + c.y * h1.y + c.z * h1.z + c.w * h1.w
                   + d.x * h2.x + d.y * h2.y + d.z * h2.z + d.w * h2.w
                   + f.x * h3.x + f.y * h3.y + f.z * h3.z + f.w * h3.w;
        }

        // 4 independent 64-lane butterfly reductions (latency-hidden)
#pragma unroll
        for (int u = 0; u < 4; ++u) {
#pragma unroll
            for (int off = 32; off > 0; off >>= 1)
                acc[u] += __shfl_xor(acc[u], off, 64);
        }

        if (lane == 0) {
            f4 o = {acc[0], acc[1], acc[2], acc[3]};
            *(f4*)(out + (size_t)b * SEQ + s_base + i) = o;  // 16B aligned
        }
    }
}

// Kernel 2: in-place row softmax over SEQ for each b. One block per b.
__global__ __launch_bounds__(256) void softmax_kernel(float* __restrict__ out)
{
    const int b = blockIdx.x;
    float* row = out + (size_t)b * SEQ;
    const int t = threadIdx.x;
    const int lane = t & 63;
    const int wv = t >> 6;

    __shared__ float red_max[4];
    __shared__ float red_sum[4];

    float v[8];
    float m = -INFINITY;
#pragma unroll
    for (int j = 0; j < 8; ++j) {
        v[j] = row[t + j * 256];
        m = fmaxf(m, v[j]);
    }
#pragma unroll
    for (int off = 1; off < 64; off <<= 1)
        m = fmaxf(m, __shfl_xor(m, off, 64));
    if (lane == 0) red_max[wv] = m;
    __syncthreads();
    m = fmaxf(fmaxf(red_max[0], red_max[1]), fmaxf(red_max[2], red_max[3]));

    float sum = 0.f;
#pragma unroll
    for (int j = 0; j < 8; ++j) {
        v[j] = __expf(v[j] - m);
        sum += v[j];
    }
#pragma unroll
    for (int off = 1; off < 64; off <<= 1)
        sum += __shfl_xor(sum, off, 64);
    if (lane == 0) red_sum[wv] = sum;
    __syncthreads();
    sum = (red_sum[0] + red_sum[1]) + (red_sum[2] + red_sum[3]);

    const float inv = 1.0f / sum;
#pragma unroll
    for (int j = 0; j < 8; ++j)
        row[t + j * 256] = v[j] * inv;
}

extern "C" void kernel_launch(void* const* d_in, const int* in_sizes, int n_in,
                              void* d_out, int out_size, void* d_ws, size_t ws_size,
                              hipStream_t stream) {
    const float* hidden = (const float*)d_in[0];   // [1, 64, 1024]
    const float* enc    = (const float*)d_in[1];   // [2048, 64, 1024]
    float* out          = (float*)d_out;           // [64, 1, 2048]

    energies_kernel<<<CHUNKS * BATCH, 256, 0, stream>>>(hidden, enc, out);
    softmax_kernel<<<BATCH, 256, 0, stream>>>(out);
}